// Round 3
// baseline (69.683 us; speedup 1.0000x reference)
//
#include <hip/hip_runtime.h>

#define C_IN 256
#define HC   128
#define HW   4096
#define TP   32     // pixels per tile

#define SX 260      // u16 stride, X LDS rows [pixel][k]
#define SH 132      // u16 stride, H LDS rows [pixel][k]
#define SO 36       // f32 stride, out-staging rows

typedef __attribute__((ext_vector_type(8))) short short8;
typedef __attribute__((ext_vector_type(4))) short short4v;
typedef __attribute__((ext_vector_type(4))) float f32x4;
typedef __attribute__((ext_vector_type(4))) unsigned short u16x4;

__device__ __forceinline__ unsigned short f2bf(float f) {
    union { float f; unsigned int u; } v; v.f = f;
    return (unsigned short)((v.u + 0x7FFFu + ((v.u >> 16) & 1u)) >> 16);
}

// tanh-form GELU: max |err| vs exact-erf gelu ~3e-3, far under threshold.
__device__ __forceinline__ float gelu_f(float v) {
    const float u = v * (0.7978845608028654f + 0.035677408136300125f * v * v);
    const float e = __expf(2.0f * u);
    const float t = 1.0f - 2.0f * __builtin_amdgcn_rcpf(e + 1.0f);
    return 0.5f * v * (1.0f + t);
}

// Wave-local LDS fence: Ob is per-wave, no block barrier needed (rule #18 fence).
__device__ __forceinline__ void wave_lds_fence() {
    asm volatile("s_waitcnt lgkmcnt(0)" ::: "memory");
    __builtin_amdgcn_sched_barrier(0);
}

__global__ void convert_weights(const float* __restrict__ W1, const float* __restrict__ W2,
                                unsigned short* __restrict__ W1b, unsigned short* __restrict__ W2b) {
    int i = blockIdx.x * blockDim.x + threadIdx.x;
    if (i < HC * C_IN) { W1b[i] = f2bf(W1[i]); W2b[i] = f2bf(W2[i]); }
}

union SmemU {
    unsigned short Xs[TP * SX];                                    // 16640 B
    struct { unsigned short Hs[TP * SH]; float Ob[4][16][SO]; } u2; // 8448 + 9216
};

template<bool USE_WS>
__global__ __launch_bounds__(256, 8) void fused_mlp(
    const float* __restrict__ x,
    const float* __restrict__ W1, const float* __restrict__ b1,
    const float* __restrict__ g1, const float* __restrict__ be1,
    const float* __restrict__ W2, const float* __restrict__ b2,
    const float* __restrict__ g2, const float* __restrict__ be2,
    const unsigned short* __restrict__ W1b, const unsigned short* __restrict__ W2b,
    float* __restrict__ out)
{
    __shared__ alignas(16) SmemU sm;
    __shared__ float red[4][TP][2];

    const int tid = threadIdx.x;
    const int wv  = tid >> 6;
    const int l   = tid & 63;
    const int l15 = l & 15;
    const int kg  = l >> 4;     // 0..3

    const int tile = blockIdx.x;
    const int b    = tile >> 7;            // 128 tiles per batch image
    const int p0   = (tile & 127) * TP;
    const float* xb = x   + (size_t)b * (C_IN * HW) + p0;
    float*       ob = out + (size_t)b * (C_IN * HW) + p0;

    // ---- stage X: fp32 [c][p] -> bf16 LDS [p][c] ----
    {
        const int g  = tid & 7;        // pixel quad 0..7
        const int cq = tid >> 3;       // channel quad 0..31
        #pragma unroll
        for (int rnd = 0; rnd < 2; ++rnd) {
            const int c0 = rnd * 128 + cq * 4;
            f32x4 v[4];
            #pragma unroll
            for (int j = 0; j < 4; ++j)
                v[j] = *reinterpret_cast<const f32x4*>(xb + (size_t)(c0 + j) * HW + g * 4);
            #pragma unroll
            for (int jj = 0; jj < 4; ++jj) {
                u16x4 pk;
                #pragma unroll
                for (int j = 0; j < 4; ++j) pk[j] = f2bf(v[j][jj]);
                *reinterpret_cast<u16x4*>(&sm.Xs[(size_t)(g * 4 + jj) * SX + c0]) = pk;
            }
        }
    }
    __syncthreads();

    // ---- GEMM1: H(128x32) = W1(128x256) @ X(256x32) ----
    f32x4 acc1[2][2];
    const f32x4 vzero = {0.f, 0.f, 0.f, 0.f};
    #pragma unroll
    for (int mt = 0; mt < 2; ++mt)
        #pragma unroll
        for (int nt = 0; nt < 2; ++nt) acc1[mt][nt] = vzero;

    const int r0 = wv * 32;
    #pragma unroll
    for (int ks = 0; ks < 8; ++ks) {
        const int kb = ks * 32 + kg * 8;
        short8 a[2]; short4v blo[2], bhi[2];
        #pragma unroll
        for (int mt = 0; mt < 2; ++mt) {
            const int row = r0 + mt * 16 + l15;
            if constexpr (USE_WS) {
                a[mt] = *reinterpret_cast<const short8*>(W1b + (size_t)row * C_IN + kb);
            } else {
                const float* wp = W1 + (size_t)row * C_IN + kb;
                const f32x4 f0 = *reinterpret_cast<const f32x4*>(wp);
                const f32x4 f1 = *reinterpret_cast<const f32x4*>(wp + 4);
                #pragma unroll
                for (int e = 0; e < 4; ++e) { a[mt][e] = (short)f2bf(f0[e]); a[mt][4+e] = (short)f2bf(f1[e]); }
            }
        }
        #pragma unroll
        for (int nt = 0; nt < 2; ++nt) {
            const unsigned short* p = &sm.Xs[(size_t)(nt * 16 + l15) * SX + kb];
            blo[nt] = *reinterpret_cast<const short4v*>(p);
            bhi[nt] = *reinterpret_cast<const short4v*>(p + 4);
        }
        #pragma unroll
        for (int mt = 0; mt < 2; ++mt)
            #pragma unroll
            for (int nt = 0; nt < 2; ++nt) {
                const short8 bf = __builtin_shufflevector(blo[nt], bhi[nt], 0,1,2,3,4,5,6,7);
                acc1[mt][nt] = __builtin_amdgcn_mfma_f32_16x16x32_bf16(a[mt], bf, acc1[mt][nt], 0, 0, 0);
            }
    }

    // bias1 + LN1 partials
    #pragma unroll
    for (int mt = 0; mt < 2; ++mt) {
        const f32x4 bias = *reinterpret_cast<const f32x4*>(b1 + r0 + mt * 16 + kg * 4);
        #pragma unroll
        for (int nt = 0; nt < 2; ++nt) acc1[mt][nt] += bias;
    }
    #pragma unroll
    for (int nt = 0; nt < 2; ++nt) {
        float s = 0.f, q = 0.f;
        #pragma unroll
        for (int mt = 0; mt < 2; ++mt)
            #pragma unroll
            for (int r = 0; r < 4; ++r) { const float v = acc1[mt][nt][r]; s += v; q += v * v; }
        s += __shfl_xor(s, 16); s += __shfl_xor(s, 32);
        q += __shfl_xor(q, 16); q += __shfl_xor(q, 32);
        if (kg == 0) { red[wv][nt * 16 + l15][0] = s; red[wv][nt * 16 + l15][1] = q; }
    }
    __syncthreads();   // red ready; Xs reads done -> Hs (alias) writable

    // LN1 apply + gelu -> Hs
    {
        f32x4 gm[2], bt[2];
        #pragma unroll
        for (int mt = 0; mt < 2; ++mt) {
            gm[mt] = *reinterpret_cast<const f32x4*>(g1  + r0 + mt * 16 + kg * 4);
            bt[mt] = *reinterpret_cast<const f32x4*>(be1 + r0 + mt * 16 + kg * 4);
        }
        #pragma unroll
        for (int nt = 0; nt < 2; ++nt) {
            const int col = nt * 16 + l15;
            float s = 0.f, q = 0.f;
            #pragma unroll
            for (int w2 = 0; w2 < 4; ++w2) { s += red[w2][col][0]; q += red[w2][col][1]; }
            const float mean = s * (1.0f / HC);
            const float rstd = rsqrtf(q * (1.0f / HC) - mean * mean + 1e-5f);
            #pragma unroll
            for (int mt = 0; mt < 2; ++mt) {
                u16x4 pk;
                #pragma unroll
                for (int r = 0; r < 4; ++r) {
                    float v = (acc1[mt][nt][r] - mean) * rstd;
                    v = v * gm[mt][r] + bt[mt][r];
                    pk[r] = f2bf(gelu_f(v));
                }
                *reinterpret_cast<u16x4*>(&sm.u2.Hs[(size_t)col * SH + r0 + mt * 16 + kg * 4]) = pk;
            }
        }
    }
    __syncthreads();

    // ---- GEMM2: Y(256x32) = W2(256x128) @ H(128x32) ----
    f32x4 acc2[4][2];
    #pragma unroll
    for (int mt = 0; mt < 4; ++mt)
        #pragma unroll
        for (int nt = 0; nt < 2; ++nt) acc2[mt][nt] = vzero;

    const int r2 = wv * 64;
    #pragma unroll
    for (int ks = 0; ks < 4; ++ks) {
        const int kb = ks * 32 + kg * 8;
        short4v blo[2], bhi[2];
        #pragma unroll
        for (int nt = 0; nt < 2; ++nt) {
            const unsigned short* p = &sm.u2.Hs[(size_t)(nt * 16 + l15) * SH + kb];
            blo[nt] = *reinterpret_cast<const short4v*>(p);
            bhi[nt] = *reinterpret_cast<const short4v*>(p + 4);
        }
        #pragma unroll
        for (int half = 0; half < 2; ++half) {      // mt pairs to cap VGPR pressure
            short8 a[2];
            #pragma unroll
            for (int m2 = 0; m2 < 2; ++m2) {
                const int row = r2 + (half * 2 + m2) * 16 + l15;
                if constexpr (USE_WS) {
                    a[m2] = *reinterpret_cast<const short8*>(W2b + (size_t)row * HC + kb);
                } else {
                    const float* wp = W2 + (size_t)row * HC + kb;
                    const f32x4 f0 = *reinterpret_cast<const f32x4*>(wp);
                    const f32x4 f1 = *reinterpret_cast<const f32x4*>(wp + 4);
                    #pragma unroll
                    for (int e = 0; e < 4; ++e) { a[m2][e] = (short)f2bf(f0[e]); a[m2][4+e] = (short)f2bf(f1[e]); }
                }
            }
            #pragma unroll
            for (int m2 = 0; m2 < 2; ++m2)
                #pragma unroll
                for (int nt = 0; nt < 2; ++nt) {
                    const short8 bf = __builtin_shufflevector(blo[nt], bhi[nt], 0,1,2,3,4,5,6,7);
                    acc2[half * 2 + m2][nt] = __builtin_amdgcn_mfma_f32_16x16x32_bf16(a[m2], bf, acc2[half * 2 + m2][nt], 0, 0, 0);
                }
        }
    }

    // bias2 + LN2 partials
    #pragma unroll
    for (int mt = 0; mt < 4; ++mt) {
        const f32x4 bias = *reinterpret_cast<const f32x4*>(b2 + r2 + mt * 16 + kg * 4);
        #pragma unroll
        for (int nt = 0; nt < 2; ++nt) acc2[mt][nt] += bias;
    }
    #pragma unroll
    for (int nt = 0; nt < 2; ++nt) {
        float s = 0.f, q = 0.f;
        #pragma unroll
        for (int mt = 0; mt < 4; ++mt)
            #pragma unroll
            for (int r = 0; r < 4; ++r) { const float v = acc2[mt][nt][r]; s += v; q += v * v; }
        s += __shfl_xor(s, 16); s += __shfl_xor(s, 32);
        q += __shfl_xor(q, 16); q += __shfl_xor(q, 32);
        if (kg == 0) { red[wv][nt * 16 + l15][0] = s; red[wv][nt * 16 + l15][1] = q; }
    }
    __syncthreads();   // red ready; Hs reads done everywhere -> Ob (alias) writable

    float mean2[2], rstd2[2];
    #pragma unroll
    for (int nt = 0; nt < 2; ++nt) {
        const int col = nt * 16 + l15;
        float s = 0.f, q = 0.f;
        #pragma unroll
        for (int w2 = 0; w2 < 4; ++w2) { s += red[w2][col][0]; q += red[w2][col][1]; }
        mean2[nt] = s * (1.0f / C_IN);
        rstd2[nt] = rsqrtf(q * (1.0f / C_IN) - mean2[nt] * mean2[nt] + 1e-5f);
    }

    // epilogue: per-wave LDS transpose (wave-local fences only) -> full-line stores
    #pragma unroll
    for (int mt = 0; mt < 4; ++mt) {
        const f32x4 gm = *reinterpret_cast<const f32x4*>(g2  + r2 + mt * 16 + kg * 4);
        const f32x4 bt = *reinterpret_cast<const f32x4*>(be2 + r2 + mt * 16 + kg * 4);
        #pragma unroll
        for (int nt = 0; nt < 2; ++nt) {
            #pragma unroll
            for (int r = 0; r < 4; ++r) {
                float v = (acc2[mt][nt][r] - mean2[nt]) * rstd2[nt];
                v = v * gm[r] + bt[r];
                sm.u2.Ob[wv][kg * 4 + r][nt * 16 + l15] = v;
            }
        }
        wave_lds_fence();
        #pragma unroll
        for (int m = 0; m < 2; ++m) {
            const int rl  = (l >> 3) + 8 * m;          // 0..15
            const int cq4 = (l & 7) * 4;               // 0..28
            const int row = r2 + mt * 16 + rl;
            const f32x4 y4 = *reinterpret_cast<const f32x4*>(&sm.u2.Ob[wv][rl][cq4]);
            const f32x4 x4 = *reinterpret_cast<const f32x4*>(xb + (size_t)row * HW + cq4);
            f32x4 o4;
            #pragma unroll
            for (int e = 0; e < 4; ++e) o4[e] = gelu_f(y4[e] + x4[e]);
            *reinterpret_cast<f32x4*>(ob + (size_t)row * HW + cq4) = o4;
        }
        if (mt < 3) wave_lds_fence();   // WAR: reads done before next mt's writes
    }
}

extern "C" void kernel_launch(void* const* d_in, const int* in_sizes, int n_in,
                              void* d_out, int out_size, void* d_ws, size_t ws_size,
                              hipStream_t stream) {
    const float* x   = (const float*)d_in[0];
    const float* W1  = (const float*)d_in[1];
    const float* b1  = (const float*)d_in[2];
    const float* g1  = (const float*)d_in[3];
    const float* be1 = (const float*)d_in[4];
    const float* W2  = (const float*)d_in[5];
    const float* b2  = (const float*)d_in[6];
    const float* g2  = (const float*)d_in[7];
    const float* be2 = (const float*)d_in[8];
    float* out = (float*)d_out;

    const size_t need = (size_t)(HC * C_IN + C_IN * HC) * sizeof(unsigned short);
    if (ws_size >= need) {
        unsigned short* W1b = (unsigned short*)d_ws;
        unsigned short* W2b = W1b + HC * C_IN;
        convert_weights<<<128, 256, 0, stream>>>(W1, W2, W1b, W2b);
        fused_mlp<true><<<2048, 256, 0, stream>>>(x, W1, b1, g1, be1, W2, b2, g2, be2, W1b, W2b, out);
    } else {
        fused_mlp<false><<<2048, 256, 0, stream>>>(x, W1, b1, g1, be1, W2, b2, g2, be2, nullptr, nullptr, out);
    }
}